// Round 4
// baseline (359.692 us; speedup 1.0000x reference)
//
#include <hip/hip_runtime.h>
#include <math.h>

#define BSZ 4096
#define DIM 1024
#define NST 2900000

constexpr float GAMMA_S   = 0.8f;
constexpr float GAMMA_U   = 0.8f;
constexpr float RHO_I_C   = 0.1f;
constexpr float RHO_T_C   = 0.1f;
constexpr float C_EPS     = 1e-10f;
constexpr float TAU_MIN_C = 0.005f;
constexpr float TAU_MAX_C = 1.0f;
constexpr float GCLIP     = 5.0f;
constexpr float ETA_INIT_C = 0.01f;
constexpr float ETA_MIN_C  = 1e-4f;
constexpr float PI_F       = 3.14159265358979323846f;

typedef __bf16 bf16x8 __attribute__((ext_vector_type(8)));
typedef float  f32x4  __attribute__((ext_vector_type(4)));

__device__ __forceinline__ unsigned short f2bf(float f) {
    unsigned int u = __float_as_uint(f);
    u += 0x7fffu + ((u >> 16) & 1u);
    return (unsigned short)(u >> 16);
}
__device__ __forceinline__ float bf2f(unsigned short s) {
    return __uint_as_float(((unsigned int)s) << 16);
}

// ---------------------------------------------------------------------------
// conv_diag: fp32->bf16 both feature matrices + bf16-consistent diag dot +
// gather taus/old_b.  One wave per row, 4 rows per block.
// ---------------------------------------------------------------------------
__global__ __launch_bounds__(256) void conv_diag(const float* __restrict__ imf,
                                                 const float* __restrict__ txf,
                                                 unsigned short* __restrict__ abf,
                                                 unsigned short* __restrict__ bbf,
                                                 const float* __restrict__ tau_I,
                                                 const float* __restrict__ tau_T,
                                                 const float* __restrict__ b_I,
                                                 const float* __restrict__ b_T,
                                                 const int* __restrict__ iid,
                                                 const int* __restrict__ tid_,
                                                 float* diag, float* tauIg, float* tauTg,
                                                 float* obI, float* obT) {
    const int w  = threadIdx.x >> 6;
    const int ln = threadIdx.x & 63;
    const int i  = blockIdx.x * 4 + w;          // row
    float dot = 0.f;
#pragma unroll
    for (int k = 0; k < 4; ++k) {
        const int off = i * DIM + k * 256 + ln * 4;
        float4 a = *(const float4*)&imf[off];
        float4 b = *(const float4*)&txf[off];
        ushort4 ra, rb;
        ra.x = f2bf(a.x); ra.y = f2bf(a.y); ra.z = f2bf(a.z); ra.w = f2bf(a.w);
        rb.x = f2bf(b.x); rb.y = f2bf(b.y); rb.z = f2bf(b.z); rb.w = f2bf(b.w);
        *(ushort4*)&abf[off] = ra;
        *(ushort4*)&bbf[off] = rb;
        dot += bf2f(ra.x) * bf2f(rb.x) + bf2f(ra.y) * bf2f(rb.y) +
               bf2f(ra.z) * bf2f(rb.z) + bf2f(ra.w) * bf2f(rb.w);
    }
#pragma unroll
    for (int m = 32; m; m >>= 1) dot += __shfl_xor(dot, m);
    if (ln == 0) {
        diag[i] = dot;
        const int id = iid[i];
        tauIg[i] = tau_I[id];
        obI[i]   = b_I[id];
        const int td = tid_[i];
        tauTg[i] = tau_T[td];
        obT[i]   = b_T[td];
    }
}

// ---------------------------------------------------------------------------
// gemm_copy: even blocks = bf16 MFMA GEMM tile (m97 structure, swizzled LDS,
// fused partial row/col max epilogue); odd blocks = state-array copy stripes
// (rides the HBM left idle by the GEMM).
// LDS swizzle: slot kc of row r holds global k-chunk kc ^ ((r>>1)&3), so the
// fragment ds_read_b128 of 16 consecutive rows spreads over all 32 banks at
// 2-way aliasing (free) instead of 8-way. global_load_lds dest stays the
// mandatory contiguous chunk layout [m104]; only the global source swizzles.
// ---------------------------------------------------------------------------
__device__ __forceinline__ void async16(const void* g, void* l) {
    __builtin_amdgcn_global_load_lds(
        (const __attribute__((address_space(1))) void*)g,
        (__attribute__((address_space(3))) void*)l, 16, 0, 0);
}

__global__ __launch_bounds__(256) void gemm_copy(const unsigned short* __restrict__ A,
                                                 const unsigned short* __restrict__ B,
                                                 float* __restrict__ C,
                                                 float* __restrict__ rp,
                                                 float* __restrict__ cp,
                                                 const float* __restrict__ s_I,
                                                 const float* __restrict__ s_T,
                                                 const float* __restrict__ u_I,
                                                 const float* __restrict__ u_T,
                                                 const float* __restrict__ b_I,
                                                 const float* __restrict__ b_T,
                                                 const float* __restrict__ tau_I,
                                                 const float* __restrict__ tau_T,
                                                 float* __restrict__ outbase) {
    __shared__ unsigned short As[128 * 32];
    __shared__ unsigned short Bs[128 * 32];

    const int tid = threadIdx.x;

    if (blockIdx.x & 1) {
        // ---------------- copy path ----------------
        const size_t idx = (size_t)(blockIdx.x >> 1) * 256 + tid;
        const size_t stride = (size_t)1024 * 256;
        const size_t NV = (NST - 1) / 4;
        const float* srcs[8] = {s_I, s_T, u_I, u_T, b_I, b_T, tau_I, tau_T};
#pragma unroll
        for (int a = 0; a < 8; ++a) {
            const float* s = srcs[a];
            float* d = outbase + (size_t)a * NST;
            for (size_t cidx = idx; cidx < NV; cidx += stride) {
                const size_t e = 1 + 4 * cidx;
                float4 v = make_float4(s[e], s[e + 1], s[e + 2], s[e + 3]);
                *(float4*)&d[e] = v;
            }
            if (idx == 0) d[0] = s[0];
            if (idx < 3)  d[NST - 3 + idx] = s[NST - 3 + idx];
        }
        return;
    }

    // ---------------- gemm path ----------------
    const int gb = blockIdx.x >> 1;          // 0..1023
    const int bjIdx = gb & 31, biIdx = gb >> 5;
    const int bi = biIdx * 128;
    const int bj = bjIdx * 128;
    const int lane = tid & 63;
    const int wave = tid >> 6;
    const int m_base = (wave >> 1) * 64;
    const int n_base = (wave & 1) * 64;

    // staging: chunk c -> LDS row c>>2, slot c&3; global k-chunk = slot ^ ((row>>1)&3)
    const int c0 = tid, c1 = tid + 256;
    const int r0 = c0 >> 2, kg0 = ((c0 & 3) ^ ((r0 >> 1) & 3)) * 8;
    const int r1 = c1 >> 2, kg1 = ((c1 & 3) ^ ((r1 >> 1) & 3)) * 8;

    f32x4 acc[4][4];
#pragma unroll
    for (int m = 0; m < 4; ++m)
#pragma unroll
        for (int n = 0; n < 4; ++n)
            acc[m][n] = (f32x4){0.f, 0.f, 0.f, 0.f};

    const int mrow = lane & 15;
    const int q    = lane >> 4;              // k-quarter

    for (int k0 = 0; k0 < DIM; k0 += 32) {
        __syncthreads();
        async16(&A[(size_t)(bi + r0) * DIM + k0 + kg0], &As[c0 * 8]);
        async16(&A[(size_t)(bi + r1) * DIM + k0 + kg1], &As[c1 * 8]);
        async16(&B[(size_t)(bj + r0) * DIM + k0 + kg0], &Bs[c0 * 8]);
        async16(&B[(size_t)(bj + r1) * DIM + k0 + kg1], &Bs[c1 * 8]);
        __syncthreads();

        bf16x8 af[4], bfr[4];
#pragma unroll
        for (int t = 0; t < 4; ++t) {
            const int rlA = m_base + t * 16 + mrow;
            const int rlB = n_base + t * 16 + mrow;
            af[t]  = *(const bf16x8*)&As[rlA * 32 + (q ^ ((rlA >> 1) & 3)) * 8];
            bfr[t] = *(const bf16x8*)&Bs[rlB * 32 + (q ^ ((rlB >> 1) & 3)) * 8];
        }
#pragma unroll
        for (int mt = 0; mt < 4; ++mt)
#pragma unroll
            for (int nt = 0; nt < 4; ++nt)
                acc[mt][nt] = __builtin_amdgcn_mfma_f32_16x16x32_bf16(
                    af[mt], bfr[nt], acc[mt][nt], 0, 0, 0);
    }

    // C/D layout: col = lane&15, row = (lane>>4)*4 + r   [m89 verified]
    const int col  = lane & 15;
    const int rowq = (lane >> 4) * 4;
#pragma unroll
    for (int mt = 0; mt < 4; ++mt)
#pragma unroll
        for (int nt = 0; nt < 4; ++nt)
#pragma unroll
            for (int r = 0; r < 4; ++r)
                C[(size_t)(bi + m_base + mt * 16 + rowq + r) * BSZ +
                  bj + n_base + nt * 16 + col] = acc[mt][nt][r];

    // ---- fused partial max epilogue ----
    float rm[4][4];
#pragma unroll
    for (int mt = 0; mt < 4; ++mt)
#pragma unroll
        for (int r = 0; r < 4; ++r) {
            float v = fmaxf(fmaxf(acc[mt][0][r], acc[mt][1][r]),
                            fmaxf(acc[mt][2][r], acc[mt][3][r]));
#pragma unroll
            for (int m = 1; m <= 8; m <<= 1) v = fmaxf(v, __shfl_xor(v, m));
            rm[mt][r] = v;
        }
    float cm[4];
#pragma unroll
    for (int nt = 0; nt < 4; ++nt) {
        float v = -INFINITY;
#pragma unroll
        for (int mt = 0; mt < 4; ++mt)
#pragma unroll
            for (int r = 0; r < 4; ++r) v = fmaxf(v, acc[mt][nt][r]);
        v = fmaxf(v, __shfl_xor(v, 16));
        v = fmaxf(v, __shfl_xor(v, 32));
        cm[nt] = v;
    }
    __syncthreads();
    float* red = (float*)As;
    if ((lane & 15) == 0) {
        const int g = lane >> 4;
#pragma unroll
        for (int mt = 0; mt < 4; ++mt)
#pragma unroll
            for (int r = 0; r < 4; ++r)
                red[wave * 64 + mt * 16 + g * 4 + r] = rm[mt][r];
    }
    if (lane < 16) {
#pragma unroll
        for (int nt = 0; nt < 4; ++nt)
            red[256 + wave * 64 + nt * 16 + lane] = cm[nt];
    }
    __syncthreads();
    if (tid < 128) {
        const int row = tid;
        const int hi = row >> 6;
        float v = fmaxf(red[(hi * 2) * 64 + (row & 63)],
                        red[(hi * 2 + 1) * 64 + (row & 63)]);
        rp[(size_t)bjIdx * BSZ + bi + row] = v;
    } else {
        const int colg = tid - 128;
        const int hi = colg >> 6;
        float v = fmaxf(red[256 + hi * 64 + (colg & 63)],
                        red[256 + (hi + 2) * 64 + (colg & 63)]);
        cp[(size_t)biIdx * BSZ + bj + colg] = v;
    }
}

// ---------------------------------------------------------------------------
// fused_sum: ONE pass over sim producing both row partials (image side) and
// col partials (text side) of (sum e, sum e*v). nb recomputed per block from
// rp/cp (L2-resident). Block (0,0) zeroes the 3 scalar outputs for finalize's
// atomics. Block: 64 cols x 4 row-waves over 64 cols x 256 rows.
// ---------------------------------------------------------------------------
__global__ __launch_bounds__(256) void fused_sum(const float* __restrict__ sim,
                                                 const float* __restrict__ diag,
                                                 const float* __restrict__ tauIg,
                                                 const float* __restrict__ tauTg,
                                                 const float* __restrict__ obI,
                                                 const float* __restrict__ obT,
                                                 const float* __restrict__ rp,
                                                 const float* __restrict__ cp,
                                                 float* __restrict__ rpsE,
                                                 float* __restrict__ rpsEI,
                                                 float* __restrict__ cpsE,
                                                 float* __restrict__ cpsEI,
                                                 float* __restrict__ out) {
    const int ln = threadIdx.x & 63;
    const int w  = threadIdx.x >> 6;
    const int c  = blockIdx.x * 64 + ln;
    const int rbeg = blockIdx.y * 256;
    const int t = threadIdx.x;

    __shared__ float sdg[256], sit[256], sb[256], snbT[64];
    {
        const int r = rbeg + t;
        float mr = -INFINITY;
#pragma unroll
        for (int k = 0; k < 32; ++k) mr = fmaxf(mr, rp[(size_t)k * BSZ + r]);
        const float dgr = diag[r];
        const float taur = tauIg[r];
        sdg[t] = dgr;
        sit[t] = 1.0f / taur;
        sb[t]  = fmaxf(obI[r], (mr - dgr) / taur);
    }
    if (t < 64) {
        const int cc = blockIdx.x * 64 + t;
        float mc = -INFINITY;
#pragma unroll
        for (int k = 0; k < 32; ++k) mc = fmaxf(mc, cp[(size_t)k * BSZ + cc]);
        snbT[t] = fmaxf(obT[cc], (mc - diag[cc]) / tauTg[cc]);
    }
    if (blockIdx.x == 0 && blockIdx.y == 0 && t < 3) out[4 * BSZ + t] = 0.f;
    const float dgc = diag[c];
    const float itc = 1.0f / tauTg[c];
    __syncthreads();
    const float bc = snbT[ln];

    float ceT = 0.f, ceiT = 0.f;
    for (int lr = w; lr < 256; lr += 4) {
        const int r = rbeg + lr;
        const float s = sim[(size_t)r * BSZ + c];
        // image (row) side
        const float vI = (s - sdg[lr]) * sit[lr];
        const float eI = __expf(vI - sb[lr]);
        float se = eI, sei = eI * vI;
#pragma unroll
        for (int m = 1; m <= 32; m <<= 1) {
            se  += __shfl_xor(se, m);
            sei += __shfl_xor(sei, m);
        }
        if (ln == 0) {
            rpsE [(size_t)blockIdx.x * BSZ + r] = se;
            rpsEI[(size_t)blockIdx.x * BSZ + r] = sei;
        }
        // text (col) side
        const float vT = (s - dgc) * itc;
        const float eT = __expf(vT - bc);
        ceT  += eT;
        ceiT += eT * vT;
    }
    __shared__ float l1[4][64], l2[4][64];
    l1[w][ln] = ceT;
    l2[w][ln] = ceiT;
    __syncthreads();
    if (t < 64) {
        cpsE [(size_t)blockIdx.y * BSZ + blockIdx.x * 64 + t] =
            l1[0][t] + l1[1][t] + l1[2][t] + l1[3][t];
        cpsEI[(size_t)blockIdx.y * BSZ + blockIdx.x * 64 + t] =
            l2[0][t] + l2[1][t] + l2[2][t] + l2[3][t];
    }
}

// ---------------------------------------------------------------------------
// Finalize: per batch position compute g, s_new, grad_tau, u_new, tau_new;
// scatter into state copies; block-reduce + atomicAdd the 3 scalars.
// ---------------------------------------------------------------------------
__global__ __launch_bounds__(256) void finalize(const float* __restrict__ s_I,
                                                const float* __restrict__ s_T,
                                                const float* __restrict__ u_I,
                                                const float* __restrict__ u_T,
                                                const int* __restrict__ iid,
                                                const int* __restrict__ tid_,
                                                const int* __restrict__ epoch,
                                                const int* __restrict__ maxep,
                                                const float* __restrict__ diag,
                                                const float* __restrict__ tauIg,
                                                const float* __restrict__ tauTg,
                                                const float* __restrict__ obI,
                                                const float* __restrict__ obT,
                                                const float* __restrict__ rp,
                                                const float* __restrict__ cp,
                                                const float* __restrict__ rpsE,
                                                const float* __restrict__ rpsEI,
                                                const float* __restrict__ cpsE,
                                                const float* __restrict__ cpsEI,
                                                float* __restrict__ out) {
    const int i = blockIdx.x * 256 + threadIdx.x;

    const float eta = ETA_MIN_C + (ETA_INIT_C - ETA_MIN_C) *
                      cosf(0.5f * PI_F * ((float)epoch[0] / (float)maxep[0]));
    const float invBm1 = 1.0f / (float)(BSZ - 1);
    const float invB   = 1.0f / (float)BSZ;

    float* o_gI   = out;
    float* o_gT   = out + BSZ;
    float* o_gti  = out + 2 * BSZ;
    float* o_gtt  = out + 3 * BSZ;
    float* o_sI   = out + 4 * BSZ + 3;
    float* o_sT   = o_sI + NST;
    float* o_uI   = o_sT + NST;
    float* o_uT   = o_uI + NST;
    float* o_bI   = o_uT + NST;
    float* o_bT   = o_bI + NST;
    float* o_tauI = o_bT + NST;
    float* o_tauT = o_tauI + NST;

    const float dg = diag[i];
    float lossc, tI_B, tT_B;

    // image side
    {
        const int id = iid[i];
        float mr = -INFINITY;
#pragma unroll
        for (int k = 0; k < 32; ++k) mr = fmaxf(mr, rp[(size_t)k * BSZ + i]);
        const float tau = tauIg[i];
        const float ob = obI[i];
        const float nb = fmaxf(ob, (mr - dg) / tau);
        float se = 0.f, sei = 0.f;
#pragma unroll
        for (int k = 0; k < 32; ++k) {
            se  += rpsE [(size_t)k * BSZ + i] + rpsE [(size_t)(k + 32) * BSZ + i];
            sei += rpsEI[(size_t)k * BSZ + i] + rpsEI[(size_t)(k + 32) * BSZ + i];
        }
        const float g = se * invBm1;
        const float s_new = (1.f - GAMMA_S) * s_I[id] * __expf(ob - nb) + GAMMA_S * g;
        const float W = sei * invBm1 / (s_new + C_EPS);
        const float grad = logf(s_new) + nb + RHO_I_C - W;
        lossc = tau * W;
        tI_B  = tau * invB;
        const float gc = fminf(fmaxf(grad, -GCLIP), GCLIP);
        const float u_new = (1.f - GAMMA_U) * u_I[id] + GAMMA_U * gc;
        const float tau_new = fminf(fmaxf(tau - eta * u_new, TAU_MIN_C), TAU_MAX_C);
        o_gI[i] = g;
        o_gti[i] = grad;
        o_sI[id] = s_new;
        o_uI[id] = u_new;
        o_bI[id] = nb;
        o_tauI[id] = tau_new;
    }
    // text side
    {
        const int id = tid_[i];
        float mc = -INFINITY;
#pragma unroll
        for (int k = 0; k < 32; ++k) mc = fmaxf(mc, cp[(size_t)k * BSZ + i]);
        const float tau = tauTg[i];
        const float ob = obT[i];
        const float nb = fmaxf(ob, (mc - dg) / tau);
        float se = 0.f, sei = 0.f;
#pragma unroll
        for (int k = 0; k < 16; ++k) {
            se  += cpsE [(size_t)k * BSZ + i];
            sei += cpsEI[(size_t)k * BSZ + i];
        }
        const float g = se * invBm1;
        const float s_new = (1.f - GAMMA_S) * s_T[id] * __expf(ob - nb) + GAMMA_S * g;
        const float W = sei * invBm1 / (s_new + C_EPS);
        const float grad = logf(s_new) + nb + RHO_T_C - W;
        lossc += tau * W;
        tT_B   = tau * invB;
        const float gc = fminf(fmaxf(grad, -GCLIP), GCLIP);
        const float u_new = (1.f - GAMMA_U) * u_T[id] + GAMMA_U * gc;
        const float tau_new = fminf(fmaxf(tau - eta * u_new, TAU_MIN_C), TAU_MAX_C);
        o_gT[i] = g;
        o_gtt[i] = grad;
        o_sT[id] = s_new;
        o_uT[id] = u_new;
        o_bT[id] = nb;
        o_tauT[id] = tau_new;
    }

    // scalar accumulation: loss*invB, avg taus
    float v0 = lossc * invB, v1 = tI_B, v2 = tT_B;
#pragma unroll
    for (int o = 32; o; o >>= 1) {
        v0 += __shfl_down(v0, o);
        v1 += __shfl_down(v1, o);
        v2 += __shfl_down(v2, o);
    }
    __shared__ float lds[4][3];
    const int wv = threadIdx.x >> 6, ln = threadIdx.x & 63;
    if (ln == 0) { lds[wv][0] = v0; lds[wv][1] = v1; lds[wv][2] = v2; }
    __syncthreads();
    if (threadIdx.x == 0) {
        atomicAdd(&out[4 * BSZ + 0], lds[0][0] + lds[1][0] + lds[2][0] + lds[3][0]);
        atomicAdd(&out[4 * BSZ + 1], lds[0][1] + lds[1][1] + lds[2][1] + lds[3][1]);
        atomicAdd(&out[4 * BSZ + 2], lds[0][2] + lds[1][2] + lds[2][2] + lds[3][2]);
    }
}

// ---------------------------------------------------------------------------
extern "C" void kernel_launch(void* const* d_in, const int* in_sizes, int n_in,
                              void* d_out, int out_size, void* d_ws, size_t ws_size,
                              hipStream_t stream) {
    const float* imf   = (const float*)d_in[0];
    const float* txf   = (const float*)d_in[1];
    const float* s_I   = (const float*)d_in[2];
    const float* s_T   = (const float*)d_in[3];
    const float* tau_I = (const float*)d_in[4];
    const float* tau_T = (const float*)d_in[5];
    const float* u_I   = (const float*)d_in[6];
    const float* u_T   = (const float*)d_in[7];
    const float* b_I   = (const float*)d_in[8];
    const float* b_T   = (const float*)d_in[9];
    const int* iid     = (const int*)d_in[10];
    const int* tid_    = (const int*)d_in[11];
    const int* epoch   = (const int*)d_in[12];
    const int* maxep   = (const int*)d_in[13];

    float* out = (float*)d_out;
    float* ws  = (float*)d_ws;

    float* sim  = ws;
    float* aux  = ws + (size_t)BSZ * BSZ;
    float* diag  = aux + 0 * BSZ;
    float* tauIg = aux + 1 * BSZ;
    float* tauTg = aux + 2 * BSZ;
    float* obI   = aux + 3 * BSZ;
    float* obT   = aux + 4 * BSZ;
    float* rp    = aux + 5 * BSZ;                  // 32 * BSZ
    float* cp    = rp + (size_t)32 * BSZ;          // 32 * BSZ
    float* rpsE  = cp + (size_t)32 * BSZ;          // 64 * BSZ
    float* rpsEI = rpsE + (size_t)64 * BSZ;        // 64 * BSZ
    float* cpsE  = rpsEI + (size_t)64 * BSZ;       // 16 * BSZ
    float* cpsEI = cpsE + (size_t)16 * BSZ;        // 16 * BSZ
    unsigned short* abf = (unsigned short*)(cpsEI + (size_t)16 * BSZ);
    unsigned short* bbf = abf + (size_t)BSZ * DIM;

    conv_diag<<<BSZ / 4, 256, 0, stream>>>(imf, txf, abf, bbf, tau_I, tau_T, b_I, b_T,
                                           iid, tid_, diag, tauIg, tauTg, obI, obT);
    gemm_copy<<<2048, 256, 0, stream>>>(abf, bbf, sim, rp, cp,
                                        s_I, s_T, u_I, u_T, b_I, b_T, tau_I, tau_T,
                                        out + 4 * BSZ + 3);
    fused_sum<<<dim3(BSZ / 64, BSZ / 256), 256, 0, stream>>>(sim, diag, tauIg, tauTg,
                                                             obI, obT, rp, cp,
                                                             rpsE, rpsEI, cpsE, cpsEI,
                                                             out);
    finalize<<<BSZ / 256, 256, 0, stream>>>(s_I, s_T, u_I, u_T, iid, tid_, epoch, maxep,
                                            diag, tauIg, tauTg, obI, obT, rp, cp,
                                            rpsE, rpsEI, cpsE, cpsEI, out);
}

// Round 5
// 285.966 us; speedup vs baseline: 1.2578x; 1.2578x over previous
//
#include <hip/hip_runtime.h>
#include <math.h>

#define BSZ 4096
#define DIM 1024
#define NST 2900000

constexpr float GAMMA_S   = 0.8f;
constexpr float GAMMA_U   = 0.8f;
constexpr float RHO_I_C   = 0.1f;
constexpr float RHO_T_C   = 0.1f;
constexpr float C_EPS     = 1e-10f;
constexpr float TAU_MIN_C = 0.005f;
constexpr float TAU_MAX_C = 1.0f;
constexpr float GCLIP     = 5.0f;
constexpr float ETA_INIT_C = 0.01f;
constexpr float ETA_MIN_C  = 1e-4f;
constexpr float PI_F       = 3.14159265358979323846f;

typedef __bf16 bf16x8 __attribute__((ext_vector_type(8)));
typedef float  f32x4  __attribute__((ext_vector_type(4)));

__device__ __forceinline__ unsigned short f2bf(float f) {
    unsigned int u = __float_as_uint(f);
    u += 0x7fffu + ((u >> 16) & 1u);
    return (unsigned short)(u >> 16);
}
__device__ __forceinline__ float bf2f(unsigned short s) {
    return __uint_as_float(((unsigned int)s) << 16);
}

// ---------------------------------------------------------------------------
// conv_diag: fp32->bf16 features + bf16-consistent diag dot + gathers +
// zero the 3 scalar outputs (for finalize's atomics).
// ---------------------------------------------------------------------------
__global__ __launch_bounds__(256) void conv_diag(const float* __restrict__ imf,
                                                 const float* __restrict__ txf,
                                                 unsigned short* __restrict__ abf,
                                                 unsigned short* __restrict__ bbf,
                                                 const float* __restrict__ tau_I,
                                                 const float* __restrict__ tau_T,
                                                 const float* __restrict__ b_I,
                                                 const float* __restrict__ b_T,
                                                 const int* __restrict__ iid,
                                                 const int* __restrict__ tid_,
                                                 float* diag, float* tauIg, float* tauTg,
                                                 float* obI, float* obT,
                                                 float* __restrict__ scal) {
    if (blockIdx.x == 0 && threadIdx.x < 3) scal[threadIdx.x] = 0.f;
    const int w  = threadIdx.x >> 6;
    const int ln = threadIdx.x & 63;
    const int i  = blockIdx.x * 4 + w;
    float dot = 0.f;
#pragma unroll
    for (int k = 0; k < 4; ++k) {
        const int off = i * DIM + k * 256 + ln * 4;
        float4 a = *(const float4*)&imf[off];
        float4 b = *(const float4*)&txf[off];
        ushort4 ra, rb;
        ra.x = f2bf(a.x); ra.y = f2bf(a.y); ra.z = f2bf(a.z); ra.w = f2bf(a.w);
        rb.x = f2bf(b.x); rb.y = f2bf(b.y); rb.z = f2bf(b.z); rb.w = f2bf(b.w);
        *(ushort4*)&abf[off] = ra;
        *(ushort4*)&bbf[off] = rb;
        dot += bf2f(ra.x) * bf2f(rb.x) + bf2f(ra.y) * bf2f(rb.y) +
               bf2f(ra.z) * bf2f(rb.z) + bf2f(ra.w) * bf2f(rb.w);
    }
#pragma unroll
    for (int m = 32; m; m >>= 1) dot += __shfl_xor(dot, m);
    if (ln == 0) {
        diag[i] = dot;
        const int id = iid[i];
        tauIg[i] = tau_I[id];
        obI[i]   = b_I[id];
        const int td = tid_[i];
        tauTg[i] = tau_T[td];
        obT[i]   = b_T[td];
    }
}

// ---------------------------------------------------------------------------
// gemm_fused: bf16 MFMA GEMM with ONLINE-SOFTMAX epilogue — sim is never
// written to memory. Per 128x128 block: for each of its 128 rows (over 128
// cols) and 128 cols (over 128 rows) emit (max_v, sum e, sum e*v) partials
// in v-space (v = (s - diag)/tau). finalize rescale-combines the 32 chunks.
// Copy of the 8 state arrays rides along: blocks with (blockIdx>>3)&1 == 1
// do copy stripes, so every XCD (blockIdx%8) gets an equal gemm/copy mix
// [round-4 lesson: even/odd interleave starved 4 XCDs of gemm work].
// LDS swizzle keeps bank conflicts at 0 [round-4 measured].
// ---------------------------------------------------------------------------
__device__ __forceinline__ void async16(const void* g, void* l) {
    __builtin_amdgcn_global_load_lds(
        (const __attribute__((address_space(1))) void*)g,
        (__attribute__((address_space(3))) void*)l, 16, 0, 0);
}

__global__ __launch_bounds__(256) void gemm_fused(const unsigned short* __restrict__ A,
                                                  const unsigned short* __restrict__ B,
                                                  const float* __restrict__ diag,
                                                  const float* __restrict__ tauIg,
                                                  const float* __restrict__ tauTg,
                                                  float* __restrict__ rpM,
                                                  float* __restrict__ rpE,
                                                  float* __restrict__ rpV,
                                                  float* __restrict__ cpM,
                                                  float* __restrict__ cpE,
                                                  float* __restrict__ cpV,
                                                  const float* __restrict__ s_I,
                                                  const float* __restrict__ s_T,
                                                  const float* __restrict__ u_I,
                                                  const float* __restrict__ u_T,
                                                  const float* __restrict__ b_I,
                                                  const float* __restrict__ b_T,
                                                  const float* __restrict__ tau_I,
                                                  const float* __restrict__ tau_T,
                                                  float* __restrict__ outbase) {
    __shared__ unsigned short As[128 * 32];   // 8 KB
    __shared__ unsigned short Bs[128 * 32];   // 8 KB

    const int tid = threadIdx.x;
    const int gid = ((blockIdx.x >> 4) << 3) | (blockIdx.x & 7);   // 0..1023

    if ((blockIdx.x >> 3) & 1) {
        // ---------------- copy path ----------------
        const size_t idx = (size_t)gid * 256 + tid;
        const size_t stride = (size_t)1024 * 256;
        const size_t NV = (NST - 1) / 4;
        const float* srcs[8] = {s_I, s_T, u_I, u_T, b_I, b_T, tau_I, tau_T};
#pragma unroll
        for (int a = 0; a < 8; ++a) {
            const float* s = srcs[a];
            float* d = outbase + (size_t)a * NST;
            for (size_t cidx = idx; cidx < NV; cidx += stride) {
                const size_t e = 1 + 4 * cidx;
                float4 v = make_float4(s[e], s[e + 1], s[e + 2], s[e + 3]);
                *(float4*)&d[e] = v;
            }
            if (idx == 0) d[0] = s[0];
            if (idx < 3)  d[NST - 3 + idx] = s[NST - 3 + idx];
        }
        return;
    }

    // ---------------- gemm path ----------------
    const int bjIdx = gid & 31, biIdx = gid >> 5;
    const int bi = biIdx * 128;
    const int bj = bjIdx * 128;
    const int lane = tid & 63;
    const int wave = tid >> 6;
    const int m_base = (wave >> 1) * 64;
    const int n_base = (wave & 1) * 64;

    // staging: chunk c -> LDS row c>>2, slot c&3; global k-chunk = slot ^ ((row>>1)&3)
    const int c0 = tid, c1 = tid + 256;
    const int r0 = c0 >> 2, kg0 = ((c0 & 3) ^ ((r0 >> 1) & 3)) * 8;
    const int r1 = c1 >> 2, kg1 = ((c1 & 3) ^ ((r1 >> 1) & 3)) * 8;

    f32x4 acc[4][4];
#pragma unroll
    for (int m = 0; m < 4; ++m)
#pragma unroll
        for (int n = 0; n < 4; ++n)
            acc[m][n] = (f32x4){0.f, 0.f, 0.f, 0.f};

    const int mrow = lane & 15;
    const int q    = lane >> 4;

    for (int k0 = 0; k0 < DIM; k0 += 32) {
        __syncthreads();
        async16(&A[(size_t)(bi + r0) * DIM + k0 + kg0], &As[c0 * 8]);
        async16(&A[(size_t)(bi + r1) * DIM + k0 + kg1], &As[c1 * 8]);
        async16(&B[(size_t)(bj + r0) * DIM + k0 + kg0], &Bs[c0 * 8]);
        async16(&B[(size_t)(bj + r1) * DIM + k0 + kg1], &Bs[c1 * 8]);
        __syncthreads();

        bf16x8 af[4], bfr[4];
#pragma unroll
        for (int t = 0; t < 4; ++t) {
            const int rlA = m_base + t * 16 + mrow;
            const int rlB = n_base + t * 16 + mrow;
            af[t]  = *(const bf16x8*)&As[rlA * 32 + (q ^ ((rlA >> 1) & 3)) * 8];
            bfr[t] = *(const bf16x8*)&Bs[rlB * 32 + (q ^ ((rlB >> 1) & 3)) * 8];
        }
#pragma unroll
        for (int mt = 0; mt < 4; ++mt)
#pragma unroll
            for (int nt = 0; nt < 4; ++nt)
                acc[mt][nt] = __builtin_amdgcn_mfma_f32_16x16x32_bf16(
                    af[mt], bfr[nt], acc[mt][nt], 0, 0, 0);
    }

    // ---- online-softmax epilogue ----
    __syncthreads();
    float* prm = (float*)Bs;   // [0..127]=diag row, [128..255]=itau row,
                               // [256..383]=diag col, [384..511]=itau col
    if (tid < 128) {
        prm[tid]       = diag[bi + tid];
        prm[128 + tid] = 1.0f / tauIg[bi + tid];
        prm[256 + tid] = diag[bj + tid];
        prm[384 + tid] = 1.0f / tauTg[bj + tid];
    }
    __syncthreads();

    float* red = (float*)As;   // rowM 0..255, rowE 256..511, rowV 512..767,
                               // colM 768..1023, colE 1024..1279, colV 1280..1535
    const int rowq = (lane >> 4) * 4;

    // image (row) side: C/D layout row = m_base + mt*16 + rowq + r, col varies
    // over lane&15 (16 lanes) x nt (4) = this wave's 64 cols.
#pragma unroll
    for (int mt = 0; mt < 4; ++mt)
#pragma unroll
        for (int r = 0; r < 4; ++r) {
            const int row_l = m_base + mt * 16 + rowq + r;
            const float dgr = prm[row_l];
            const float itr = prm[128 + row_l];
            float v0 = (acc[mt][0][r] - dgr) * itr;
            float v1 = (acc[mt][1][r] - dgr) * itr;
            float v2 = (acc[mt][2][r] - dgr) * itr;
            float v3 = (acc[mt][3][r] - dgr) * itr;
            float m = fmaxf(fmaxf(v0, v1), fmaxf(v2, v3));
#pragma unroll
            for (int x = 1; x <= 8; x <<= 1) m = fmaxf(m, __shfl_xor(m, x));
            const float e0 = __expf(v0 - m), e1 = __expf(v1 - m);
            const float e2 = __expf(v2 - m), e3 = __expf(v3 - m);
            float se = e0 + e1 + e2 + e3;
            float sv = e0 * v0 + e1 * v1 + e2 * v2 + e3 * v3;
#pragma unroll
            for (int x = 1; x <= 8; x <<= 1) {
                se += __shfl_xor(se, x);
                sv += __shfl_xor(sv, x);
            }
            if ((lane & 15) == 0) {
                const int idx = wave * 64 + mt * 16 + rowq + r;
                red[idx] = m; red[256 + idx] = se; red[512 + idx] = sv;
            }
        }

    // text (col) side: col = n_base + nt*16 + (lane&15); rows vary over
    // lane>>4 (4 groups) x mt x r = this wave's 64 rows.
#pragma unroll
    for (int nt = 0; nt < 4; ++nt) {
        const int col_l = n_base + nt * 16 + (lane & 15);
        const float dgc = prm[256 + col_l];
        const float itc = prm[384 + col_l];
        float m = -INFINITY;
#pragma unroll
        for (int mt = 0; mt < 4; ++mt)
#pragma unroll
            for (int r = 0; r < 4; ++r)
                m = fmaxf(m, (acc[mt][nt][r] - dgc) * itc);
        m = fmaxf(m, __shfl_xor(m, 16));
        m = fmaxf(m, __shfl_xor(m, 32));
        float se = 0.f, sv = 0.f;
#pragma unroll
        for (int mt = 0; mt < 4; ++mt)
#pragma unroll
            for (int r = 0; r < 4; ++r) {
                const float v = (acc[mt][nt][r] - dgc) * itc;
                const float e = __expf(v - m);
                se += e; sv += e * v;
            }
        se += __shfl_xor(se, 16); se += __shfl_xor(se, 32);
        sv += __shfl_xor(sv, 16); sv += __shfl_xor(sv, 32);
        if (lane < 16) {
            const int idx = wave * 64 + nt * 16 + lane;
            red[768 + idx] = m; red[1024 + idx] = se; red[1280 + idx] = sv;
        }
    }
    __syncthreads();

    if (tid < 128) {
        // rows: waves {0,1} cover rows 0..63 (col halves), {2,3} rows 64..127
        const int rg = tid, li = rg & 63;
        const int w0 = (rg >> 6) * 2, w1 = w0 + 1;
        const float mA = red[w0 * 64 + li], mB = red[w1 * 64 + li];
        const float M = fmaxf(mA, mB);
        const float fA = __expf(mA - M), fB = __expf(mB - M);
        const size_t o = (size_t)bjIdx * BSZ + bi + rg;
        rpM[o] = M;
        rpE[o] = red[256 + w0 * 64 + li] * fA + red[256 + w1 * 64 + li] * fB;
        rpV[o] = red[512 + w0 * 64 + li] * fA + red[512 + w1 * 64 + li] * fB;
    } else {
        // cols: waves {0,2} cover cols 0..63 (row halves), {1,3} cols 64..127
        const int cg = tid - 128, li = cg & 63;
        const int w0 = cg >> 6, w1 = w0 + 2;
        const float mA = red[768 + w0 * 64 + li], mB = red[768 + w1 * 64 + li];
        const float M = fmaxf(mA, mB);
        const float fA = __expf(mA - M), fB = __expf(mB - M);
        const size_t o = (size_t)biIdx * BSZ + bj + cg;
        cpM[o] = M;
        cpE[o] = red[1024 + w0 * 64 + li] * fA + red[1024 + w1 * 64 + li] * fB;
        cpV[o] = red[1280 + w0 * 64 + li] * fA + red[1280 + w1 * 64 + li] * fB;
    }
}

// ---------------------------------------------------------------------------
// Finalize: rescale-combine the 32 softmax partials per row/col, compute all
// per-position outputs, scatter state, atomic-add the 3 scalars.
// ---------------------------------------------------------------------------
__global__ __launch_bounds__(256) void finalize(const float* __restrict__ s_I,
                                                const float* __restrict__ s_T,
                                                const float* __restrict__ u_I,
                                                const float* __restrict__ u_T,
                                                const int* __restrict__ iid,
                                                const int* __restrict__ tid_,
                                                const int* __restrict__ epoch,
                                                const int* __restrict__ maxep,
                                                const float* __restrict__ tauIg,
                                                const float* __restrict__ tauTg,
                                                const float* __restrict__ obI,
                                                const float* __restrict__ obT,
                                                const float* __restrict__ rpM,
                                                const float* __restrict__ rpE,
                                                const float* __restrict__ rpV,
                                                const float* __restrict__ cpM,
                                                const float* __restrict__ cpE,
                                                const float* __restrict__ cpV,
                                                float* __restrict__ out) {
    const int i = blockIdx.x * 256 + threadIdx.x;

    const float eta = ETA_MIN_C + (ETA_INIT_C - ETA_MIN_C) *
                      cosf(0.5f * PI_F * ((float)epoch[0] / (float)maxep[0]));
    const float invBm1 = 1.0f / (float)(BSZ - 1);
    const float invB   = 1.0f / (float)BSZ;

    float* o_gI   = out;
    float* o_gT   = out + BSZ;
    float* o_gti  = out + 2 * BSZ;
    float* o_gtt  = out + 3 * BSZ;
    float* o_sI   = out + 4 * BSZ + 3;
    float* o_sT   = o_sI + NST;
    float* o_uI   = o_sT + NST;
    float* o_uT   = o_uI + NST;
    float* o_bI   = o_uT + NST;
    float* o_bT   = o_bI + NST;
    float* o_tauI = o_bT + NST;
    float* o_tauT = o_tauI + NST;

    float lossc, tI_B, tT_B;

    // image side
    {
        const int id = iid[i];
        float mr = -INFINITY;
#pragma unroll
        for (int k = 0; k < 32; ++k) mr = fmaxf(mr, rpM[(size_t)k * BSZ + i]);
        const float tau = tauIg[i];
        const float ob = obI[i];
        const float nb = fmaxf(ob, mr);
        float se = 0.f, sv = 0.f;
#pragma unroll
        for (int k = 0; k < 32; ++k) {
            const float f = __expf(rpM[(size_t)k * BSZ + i] - nb);
            se += rpE[(size_t)k * BSZ + i] * f;
            sv += rpV[(size_t)k * BSZ + i] * f;
        }
        const float g = se * invBm1;
        const float s_new = (1.f - GAMMA_S) * s_I[id] * __expf(ob - nb) + GAMMA_S * g;
        const float W = sv * invBm1 / (s_new + C_EPS);
        const float grad = logf(s_new) + nb + RHO_I_C - W;
        lossc = tau * W;
        tI_B  = tau * invB;
        const float gc = fminf(fmaxf(grad, -GCLIP), GCLIP);
        const float u_new = (1.f - GAMMA_U) * u_I[id] + GAMMA_U * gc;
        const float tau_new = fminf(fmaxf(tau - eta * u_new, TAU_MIN_C), TAU_MAX_C);
        o_gI[i] = g;
        o_gti[i] = grad;
        o_sI[id] = s_new;
        o_uI[id] = u_new;
        o_bI[id] = nb;
        o_tauI[id] = tau_new;
    }
    // text side
    {
        const int id = tid_[i];
        float mc = -INFINITY;
#pragma unroll
        for (int k = 0; k < 32; ++k) mc = fmaxf(mc, cpM[(size_t)k * BSZ + i]);
        const float tau = tauTg[i];
        const float ob = obT[i];
        const float nb = fmaxf(ob, mc);
        float se = 0.f, sv = 0.f;
#pragma unroll
        for (int k = 0; k < 32; ++k) {
            const float f = __expf(cpM[(size_t)k * BSZ + i] - nb);
            se += cpE[(size_t)k * BSZ + i] * f;
            sv += cpV[(size_t)k * BSZ + i] * f;
        }
        const float g = se * invBm1;
        const float s_new = (1.f - GAMMA_S) * s_T[id] * __expf(ob - nb) + GAMMA_S * g;
        const float W = sv * invBm1 / (s_new + C_EPS);
        const float grad = logf(s_new) + nb + RHO_T_C - W;
        lossc += tau * W;
        tT_B   = tau * invB;
        const float gc = fminf(fmaxf(grad, -GCLIP), GCLIP);
        const float u_new = (1.f - GAMMA_U) * u_T[id] + GAMMA_U * gc;
        const float tau_new = fminf(fmaxf(tau - eta * u_new, TAU_MIN_C), TAU_MAX_C);
        o_gT[i] = g;
        o_gtt[i] = grad;
        o_sT[id] = s_new;
        o_uT[id] = u_new;
        o_bT[id] = nb;
        o_tauT[id] = tau_new;
    }

    // scalars: loss mean, avg taus
    float v0 = lossc * invB, v1 = tI_B, v2 = tT_B;
#pragma unroll
    for (int o = 32; o; o >>= 1) {
        v0 += __shfl_down(v0, o);
        v1 += __shfl_down(v1, o);
        v2 += __shfl_down(v2, o);
    }
    __shared__ float lds[4][3];
    const int wv = threadIdx.x >> 6, ln = threadIdx.x & 63;
    if (ln == 0) { lds[wv][0] = v0; lds[wv][1] = v1; lds[wv][2] = v2; }
    __syncthreads();
    if (threadIdx.x == 0) {
        atomicAdd(&out[4 * BSZ + 0], lds[0][0] + lds[1][0] + lds[2][0] + lds[3][0]);
        atomicAdd(&out[4 * BSZ + 1], lds[0][1] + lds[1][1] + lds[2][1] + lds[3][1]);
        atomicAdd(&out[4 * BSZ + 2], lds[0][2] + lds[1][2] + lds[2][2] + lds[3][2]);
    }
}

// ---------------------------------------------------------------------------
extern "C" void kernel_launch(void* const* d_in, const int* in_sizes, int n_in,
                              void* d_out, int out_size, void* d_ws, size_t ws_size,
                              hipStream_t stream) {
    const float* imf   = (const float*)d_in[0];
    const float* txf   = (const float*)d_in[1];
    const float* s_I   = (const float*)d_in[2];
    const float* s_T   = (const float*)d_in[3];
    const float* tau_I = (const float*)d_in[4];
    const float* tau_T = (const float*)d_in[5];
    const float* u_I   = (const float*)d_in[6];
    const float* u_T   = (const float*)d_in[7];
    const float* b_I   = (const float*)d_in[8];
    const float* b_T   = (const float*)d_in[9];
    const int* iid     = (const int*)d_in[10];
    const int* tid_    = (const int*)d_in[11];
    const int* epoch   = (const int*)d_in[12];
    const int* maxep   = (const int*)d_in[13];

    float* out = (float*)d_out;
    float* ws  = (float*)d_ws;

    float* diag  = ws + 0 * BSZ;
    float* tauIg = ws + 1 * BSZ;
    float* tauTg = ws + 2 * BSZ;
    float* obI   = ws + 3 * BSZ;
    float* obT   = ws + 4 * BSZ;
    float* rpM   = ws + 5 * BSZ;                   // 32 * BSZ each
    float* rpE   = rpM + (size_t)32 * BSZ;
    float* rpV   = rpE + (size_t)32 * BSZ;
    float* cpM   = rpV + (size_t)32 * BSZ;
    float* cpE   = cpM + (size_t)32 * BSZ;
    float* cpV   = cpE + (size_t)32 * BSZ;
    unsigned short* abf = (unsigned short*)(cpV + (size_t)32 * BSZ);
    unsigned short* bbf = abf + (size_t)BSZ * DIM;

    conv_diag<<<BSZ / 4, 256, 0, stream>>>(imf, txf, abf, bbf, tau_I, tau_T, b_I, b_T,
                                           iid, tid_, diag, tauIg, tauTg, obI, obT,
                                           out + 4 * BSZ);
    gemm_fused<<<2048, 256, 0, stream>>>(abf, bbf, diag, tauIg, tauTg,
                                         rpM, rpE, rpV, cpM, cpE, cpV,
                                         s_I, s_T, u_I, u_T, b_I, b_T, tau_I, tau_T,
                                         out + 4 * BSZ + 3);
    finalize<<<BSZ / 256, 256, 0, stream>>>(s_I, s_T, u_I, u_T, iid, tid_, epoch, maxep,
                                            tauIg, tauTg, obI, obT,
                                            rpM, rpE, rpV, cpM, cpE, cpV, out);
}